// Round 1
// baseline (13264.801 us; speedup 1.0000x reference)
//
#include <hip/hip_runtime.h>
#include <hip/hip_bf16.h>
#include <math.h>

#define L_  12
#define H_  12
#define D_  768
#define FF_ 3072
#define V_  32000
#define T_  1024
#define B_  2
#define BT_ (B_*T_)

typedef unsigned short ushort_t;
typedef unsigned int   uint_t;
typedef __bf16 bf16x8 __attribute__((ext_vector_type(8)));
typedef float  f32x4  __attribute__((ext_vector_type(4)));

__device__ __forceinline__ uint_t f2bf1(float f) {
    uint_t u = __builtin_bit_cast(uint_t, f);
    return (u + 0x7FFFu + ((u >> 16) & 1u)) >> 16;   // RNE truncate to bf16
}
__device__ __forceinline__ uint_t f2bf2(float lo, float hi) {
    return f2bf1(lo) | (f2bf1(hi) << 16);
}

// ---------------- GEMM: C[M,N] = A[M,K] @ W[N,K]^T  (both fp32 in, bf16 MFMA) ----------------
#define EPI_NONE  0
#define EPI_RESID 1
#define EPI_GELU  2

template <int EPI>
__global__ __launch_bounds__(256) void gemm_nt(
    const float* __restrict__ A, const float* __restrict__ W,
    const float* __restrict__ R, float* __restrict__ C,
    int M, int N, int K)
{
    // 128x128 tile, 4 waves in 2x2, BK=32, 16x16x32 bf16 MFMA.
    __shared__ ushort_t As[128 * 40];   // +8 pad breaks b128-read bank conflicts
    __shared__ ushort_t Bs[128 * 40];

    const int tid  = threadIdx.x;
    const int m0   = blockIdx.y * 128;
    const int n0   = blockIdx.x * 128;
    const int wave = tid >> 6;
    const int lane = tid & 63;
    const int wm   = (wave >> 1) * 64;
    const int wn   = (wave & 1) * 64;
    const int lr   = lane & 15;          // fragment row (A) / col (B)
    const int lk   = (lane >> 4) * 8;    // fragment k-offset

    // staging: thread -> (row sr, 16 cols at sc)
    const int sr = tid >> 1;
    const int sc = (tid & 1) * 16;
    const float* ga = A + (size_t)(m0 + sr) * K + sc;
    const float* gw = W + (size_t)(n0 + sr) * K + sc;
    uint_t* la = (uint_t*)&As[sr * 40 + sc];
    uint_t* lb = (uint_t*)&Bs[sr * 40 + sc];

    f32x4 acc[4][4] = {};

    for (int k0 = 0; k0 < K; k0 += 32) {
        const float4* pa = (const float4*)(ga + k0);
        const float4* pw = (const float4*)(gw + k0);
        float4 a0 = pa[0], a1 = pa[1], a2 = pa[2], a3 = pa[3];
        float4 w0 = pw[0], w1 = pw[1], w2 = pw[2], w3 = pw[3];
        la[0] = f2bf2(a0.x, a0.y); la[1] = f2bf2(a0.z, a0.w);
        la[2] = f2bf2(a1.x, a1.y); la[3] = f2bf2(a1.z, a1.w);
        la[4] = f2bf2(a2.x, a2.y); la[5] = f2bf2(a2.z, a2.w);
        la[6] = f2bf2(a3.x, a3.y); la[7] = f2bf2(a3.z, a3.w);
        lb[0] = f2bf2(w0.x, w0.y); lb[1] = f2bf2(w0.z, w0.w);
        lb[2] = f2bf2(w1.x, w1.y); lb[3] = f2bf2(w1.z, w1.w);
        lb[4] = f2bf2(w2.x, w2.y); lb[5] = f2bf2(w2.z, w2.w);
        lb[6] = f2bf2(w3.x, w3.y); lb[7] = f2bf2(w3.z, w3.w);
        __syncthreads();

        bf16x8 av[4], bv[4];
        #pragma unroll
        for (int i = 0; i < 4; ++i)
            av[i] = *(const bf16x8*)&As[(wm + i * 16 + lr) * 40 + lk];
        #pragma unroll
        for (int j = 0; j < 4; ++j)
            bv[j] = *(const bf16x8*)&Bs[(wn + j * 16 + lr) * 40 + lk];
        #pragma unroll
        for (int i = 0; i < 4; ++i)
            #pragma unroll
            for (int j = 0; j < 4; ++j)
                acc[i][j] = __builtin_amdgcn_mfma_f32_16x16x32_bf16(av[i], bv[j], acc[i][j], 0, 0, 0);
        __syncthreads();
    }

    // epilogue: D[row][col], col = lane&15, row = (lane>>4)*4 + r  (m89/m91-verified)
    const int rbase = (lane >> 4) * 4;
    #pragma unroll
    for (int i = 0; i < 4; ++i) {
        #pragma unroll
        for (int j = 0; j < 4; ++j) {
            #pragma unroll
            for (int r = 0; r < 4; ++r) {
                int row = m0 + wm + i * 16 + rbase + r;
                int col = n0 + wn + j * 16 + lr;
                size_t idx = (size_t)row * N + col;
                float v = acc[i][j][r];
                if (EPI == EPI_RESID) v += R[idx];
                if (EPI == EPI_GELU)  v = 0.5f * v * (1.0f + erff(v * 0.70710678118654752f));
                C[idx] = v;
            }
        }
    }
}

// ---------------- causal attention, fp32, scores materialized in LDS ----------------
// qkv layout: [B, T, 3*D] ; q at h*64, k at 768 + h*64, v at 1536 + h*64
__global__ __launch_bounds__(256) void attn_kernel(const float* __restrict__ qkv,
                                                   float* __restrict__ o)
{
    __shared__ float Qs[16][64];
    __shared__ float Ks[64][68];       // K tile, reused for V tile
    __shared__ float S[16][1024];
    __shared__ float red[16][17];

    const int NQT = T_ / 16;
    const int qt = blockIdx.x % NQT;
    const int bh = blockIdx.x / NQT;
    const int h  = bh % H_;
    const int b  = bh / H_;
    const int tid = threadIdx.x;

    const float* qp = qkv + (size_t)b * T_ * 2304 + h * 64;
    const float* kp = qp + 768;
    const float* vp = qp + 1536;

    for (int i = tid; i < 16 * 64; i += 256) {
        int r = i >> 6, c = i & 63;
        Qs[r][c] = qp[(size_t)(qt * 16 + r) * 2304 + c];
    }
    const int ncols  = (qt * 16 + 16 + 63) & ~63;   // keys needed, rounded to tile
    const int ntiles = ncols >> 6;
    __syncthreads();

    const int qi  = tid >> 4;    // 0..15 q row in tile
    const int sub = tid & 15;

    for (int jt = 0; jt < ntiles; ++jt) {
        for (int i = tid; i < 64 * 64; i += 256) {
            int r = i >> 6, c = i & 63;
            Ks[r][c] = kp[(size_t)(jt * 64 + r) * 2304 + c];
        }
        __syncthreads();
        #pragma unroll
        for (int jj = 0; jj < 4; ++jj) {
            int j = sub * 4 + jj;
            float s = 0.f;
            #pragma unroll
            for (int c = 0; c < 64; ++c) s += Qs[qi][c] * Ks[j][c];
            s *= 0.125f;
            int jg = jt * 64 + j;
            if (jg > qt * 16 + qi) s = -INFINITY;   // causal mask
            S[qi][jg] = s;
        }
        __syncthreads();
    }

    // softmax over S[qi][0:ncols], 16 threads per row
    float m = -INFINITY;
    for (int j = sub; j < ncols; j += 16) m = fmaxf(m, S[qi][j]);
    red[qi][sub] = m;
    __syncthreads();
    if (sub == 0) {
        float mm = -INFINITY;
        for (int k = 0; k < 16; ++k) mm = fmaxf(mm, red[qi][k]);
        red[qi][16] = mm;
    }
    __syncthreads();
    const float rm = red[qi][16];
    float sum = 0.f;
    for (int j = sub; j < ncols; j += 16) {
        float e = __expf(S[qi][j] - rm);
        S[qi][j] = e;
        sum += e;
    }
    __syncthreads();
    red[qi][sub] = sum;
    __syncthreads();
    if (sub == 0) {
        float ss = 0.f;
        for (int k = 0; k < 16; ++k) ss += red[qi][k];
        red[qi][16] = ss;
    }
    __syncthreads();
    const float inv = 1.0f / red[qi][16];

    // PV: thread owns (qi, 4 d-cols)
    const int d0 = sub * 4;
    float o0 = 0, o1 = 0, o2 = 0, o3 = 0;
    for (int jt = 0; jt < ntiles; ++jt) {
        __syncthreads();
        for (int i = tid; i < 64 * 64; i += 256) {
            int r = i >> 6, c = i & 63;
            Ks[r][c] = vp[(size_t)(jt * 64 + r) * 2304 + c];
        }
        __syncthreads();
        #pragma unroll 8
        for (int jj = 0; jj < 64; ++jj) {
            float p = S[qi][jt * 64 + jj];
            o0 += p * Ks[jj][d0 + 0];
            o1 += p * Ks[jj][d0 + 1];
            o2 += p * Ks[jj][d0 + 2];
            o3 += p * Ks[jj][d0 + 3];
        }
    }
    float* op = o + (size_t)(b * T_ + qt * 16 + qi) * 768 + h * 64 + d0;
    op[0] = o0 * inv; op[1] = o1 * inv; op[2] = o2 * inv; op[3] = o3 * inv;
}

// ---------------- layernorm over D=768, one block per row ----------------
__global__ __launch_bounds__(256) void ln_kernel(const float* __restrict__ x,
    const float* __restrict__ w, const float* __restrict__ bia, float* __restrict__ out)
{
    const int row = blockIdx.x;
    const int tid = threadIdx.x;
    const float* xr = x + (size_t)row * 768;
    float v0 = xr[tid], v1 = xr[tid + 256], v2 = xr[tid + 512];
    float s  = v0 + v1 + v2;
    float s2 = v0 * v0 + v1 * v1 + v2 * v2;
    #pragma unroll
    for (int off = 32; off > 0; off >>= 1) {
        s  += __shfl_down(s,  off, 64);
        s2 += __shfl_down(s2, off, 64);
    }
    __shared__ float sh[8];
    const int wave = tid >> 6;
    if ((tid & 63) == 0) { sh[wave] = s; sh[4 + wave] = s2; }
    __syncthreads();
    float S  = sh[0] + sh[1] + sh[2] + sh[3];
    float S2 = sh[4] + sh[5] + sh[6] + sh[7];
    float mean = S * (1.f / 768.f);
    float var  = S2 * (1.f / 768.f) - mean * mean;
    float inv  = rsqrtf(var + 1e-5f);
    float* orow = out + (size_t)row * 768;
    orow[tid]       = (v0 - mean) * inv * w[tid]       + bia[tid];
    orow[tid + 256] = (v1 - mean) * inv * w[tid + 256] + bia[tid + 256];
    orow[tid + 512] = (v2 - mean) * inv * w[tid + 512] + bia[tid + 512];
}

// ---------------- embedding ----------------
__global__ __launch_bounds__(256) void embed_kernel(const int* __restrict__ ids,
    const float* __restrict__ tok, const float* __restrict__ pos, float* __restrict__ x)
{
    const int bt = blockIdx.x;
    const int t  = bt % T_;
    const int id = ids[bt];
    const int tid = threadIdx.x;
    const float* tr = tok + (size_t)id * 768;
    const float* pr = pos + (size_t)t * 768;
    float* xr = x + (size_t)bt * 768;
    xr[tid]       = tr[tid]       + pr[tid];
    xr[tid + 256] = tr[tid + 256] + pr[tid + 256];
    xr[tid + 512] = tr[tid + 512] + pr[tid + 512];
}

// ---------------- launcher ----------------
extern "C" void kernel_launch(void* const* d_in, const int* in_sizes, int n_in,
                              void* d_out, int out_size, void* d_ws, size_t ws_size,
                              hipStream_t stream)
{
    const int*   ids   = (const int*)  d_in[0];
    const float* tok   = (const float*)d_in[1];
    const float* pos   = (const float*)d_in[2];
    const float* ln1w  = (const float*)d_in[3];
    const float* ln1b  = (const float*)d_in[4];
    const float* qkvw  = (const float*)d_in[5];
    const float* outw  = (const float*)d_in[6];
    const float* ln2w  = (const float*)d_in[7];
    const float* ln2b  = (const float*)d_in[8];
    const float* upw   = (const float*)d_in[9];
    const float* downw = (const float*)d_in[10];
    const float* lnfw  = (const float*)d_in[11];
    const float* lnfb  = (const float*)d_in[12];
    float* out = (float*)d_out;

    // workspace layout (fp32): x, h, qkv, o, ffh  = 63 MB total
    float* x   = (float*)d_ws;
    float* h   = x   + (size_t)BT_ * D_;
    float* qkv = h   + (size_t)BT_ * D_;
    float* o   = qkv + (size_t)BT_ * 3 * D_;
    float* ffh = o   + (size_t)BT_ * D_;

    embed_kernel<<<BT_, 256, 0, stream>>>(ids, tok, pos, x);

    for (int l = 0; l < L_; ++l) {
        ln_kernel<<<BT_, 256, 0, stream>>>(x, ln1w + l * D_, ln1b + l * D_, h);
        gemm_nt<EPI_NONE><<<dim3(3 * D_ / 128, BT_ / 128), 256, 0, stream>>>(
            h, qkvw + (size_t)l * 3 * D_ * D_, nullptr, qkv, BT_, 3 * D_, D_);
        attn_kernel<<<B_ * H_ * (T_ / 16), 256, 0, stream>>>(qkv, o);
        gemm_nt<EPI_RESID><<<dim3(D_ / 128, BT_ / 128), 256, 0, stream>>>(
            o, outw + (size_t)l * D_ * D_, x, x, BT_, D_, D_);
        ln_kernel<<<BT_, 256, 0, stream>>>(x, ln2w + l * D_, ln2b + l * D_, h);
        gemm_nt<EPI_GELU><<<dim3(FF_ / 128, BT_ / 128), 256, 0, stream>>>(
            h, upw + (size_t)l * FF_ * D_, nullptr, ffh, BT_, FF_, D_);
        gemm_nt<EPI_RESID><<<dim3(D_ / 128, BT_ / 128), 256, 0, stream>>>(
            ffh, downw + (size_t)l * D_ * FF_, x, x, BT_, D_, FF_);
    }

    ln_kernel<<<BT_, 256, 0, stream>>>(x, lnfw, lnfb, h);
    gemm_nt<EPI_NONE><<<dim3(V_ / 128, BT_ / 128), 256, 0, stream>>>(
        h, tok, nullptr, out, BT_, V_, D_);
}

// Round 2
// 4196.559 us; speedup vs baseline: 3.1609x; 3.1609x over previous
//
#include <hip/hip_runtime.h>
#include <hip/hip_bf16.h>
#include <math.h>

#define L_  12
#define H_  12
#define D_  768
#define FF_ 3072
#define V_  32000
#define T_  1024
#define B_  2
#define BT_ (B_*T_)

typedef unsigned short ushort_t;
typedef unsigned int   uint_t;
typedef __bf16 bf16x8 __attribute__((ext_vector_type(8)));
typedef float  f32x4  __attribute__((ext_vector_type(4)));

__device__ __forceinline__ uint_t f2bf1(float f) {
    uint_t u = __builtin_bit_cast(uint_t, f);
    return (u + 0x7FFFu + ((u >> 16) & 1u)) >> 16;   // RNE truncate to bf16
}
__device__ __forceinline__ uint_t f2bf2(float lo, float hi) {
    return f2bf1(lo) | (f2bf1(hi) << 16);
}

// ---------------- GEMM: C[M,N] = A[M,K] @ W[N,K]^T  (both fp32 in, bf16 MFMA) ----------------
#define EPI_NONE  0
#define EPI_RESID 1
#define EPI_GELU  2

template <int EPI>
__global__ __launch_bounds__(256) void gemm_nt(
    const float* __restrict__ A, const float* __restrict__ W,
    const float* __restrict__ R, float* __restrict__ C,
    int M, int N, int K)
{
    // 128x128 tile, 4 waves in 2x2, BK=32, 16x16x32 bf16 MFMA.
    __shared__ ushort_t As[128 * 40];   // +8 pad breaks b128-read bank conflicts
    __shared__ ushort_t Bs[128 * 40];

    const int tid  = threadIdx.x;
    const int m0   = blockIdx.y * 128;
    const int n0   = blockIdx.x * 128;
    const int wave = tid >> 6;
    const int lane = tid & 63;
    const int wm   = (wave >> 1) * 64;
    const int wn   = (wave & 1) * 64;
    const int lr   = lane & 15;          // fragment row (A) / col (B)
    const int lk   = (lane >> 4) * 8;    // fragment k-offset

    // staging: thread -> (row sr, 16 cols at sc)
    const int sr = tid >> 1;
    const int sc = (tid & 1) * 16;
    const float* ga = A + (size_t)(m0 + sr) * K + sc;
    const float* gw = W + (size_t)(n0 + sr) * K + sc;
    uint_t* la = (uint_t*)&As[sr * 40 + sc];
    uint_t* lb = (uint_t*)&Bs[sr * 40 + sc];

    f32x4 acc[4][4] = {};

    for (int k0 = 0; k0 < K; k0 += 32) {
        const float4* pa = (const float4*)(ga + k0);
        const float4* pw = (const float4*)(gw + k0);
        float4 a0 = pa[0], a1 = pa[1], a2 = pa[2], a3 = pa[3];
        float4 w0 = pw[0], w1 = pw[1], w2 = pw[2], w3 = pw[3];
        la[0] = f2bf2(a0.x, a0.y); la[1] = f2bf2(a0.z, a0.w);
        la[2] = f2bf2(a1.x, a1.y); la[3] = f2bf2(a1.z, a1.w);
        la[4] = f2bf2(a2.x, a2.y); la[5] = f2bf2(a2.z, a2.w);
        la[6] = f2bf2(a3.x, a3.y); la[7] = f2bf2(a3.z, a3.w);
        lb[0] = f2bf2(w0.x, w0.y); lb[1] = f2bf2(w0.z, w0.w);
        lb[2] = f2bf2(w1.x, w1.y); lb[3] = f2bf2(w1.z, w1.w);
        lb[4] = f2bf2(w2.x, w2.y); lb[5] = f2bf2(w2.z, w2.w);
        lb[6] = f2bf2(w3.x, w3.y); lb[7] = f2bf2(w3.z, w3.w);
        __syncthreads();

        bf16x8 av[4], bv[4];
        #pragma unroll
        for (int i = 0; i < 4; ++i)
            av[i] = *(const bf16x8*)&As[(wm + i * 16 + lr) * 40 + lk];
        #pragma unroll
        for (int j = 0; j < 4; ++j)
            bv[j] = *(const bf16x8*)&Bs[(wn + j * 16 + lr) * 40 + lk];
        #pragma unroll
        for (int i = 0; i < 4; ++i)
            #pragma unroll
            for (int j = 0; j < 4; ++j)
                acc[i][j] = __builtin_amdgcn_mfma_f32_16x16x32_bf16(av[i], bv[j], acc[i][j], 0, 0, 0);
        __syncthreads();
    }

    // epilogue: D[row][col], col = lane&15, row = (lane>>4)*4 + r  (m89/m91-verified)
    const int rbase = (lane >> 4) * 4;
    #pragma unroll
    for (int i = 0; i < 4; ++i) {
        #pragma unroll
        for (int j = 0; j < 4; ++j) {
            #pragma unroll
            for (int r = 0; r < 4; ++r) {
                int row = m0 + wm + i * 16 + rbase + r;
                int col = n0 + wn + j * 16 + lr;
                size_t idx = (size_t)row * N + col;
                float v = acc[i][j][r];
                if (EPI == EPI_RESID) v += R[idx];
                if (EPI == EPI_GELU)  v = 0.5f * v * (1.0f + erff(v * 0.70710678118654752f));
                C[idx] = v;
            }
        }
    }
}

// ---------------- qkv prep: fp32 qkv -> bf16 qb[bh][t][d], kb[bh][t][d], vt[bh][d][t] ----------------
__global__ __launch_bounds__(256) void qkv_prep(const float* __restrict__ qkv,
    ushort_t* __restrict__ qb, ushort_t* __restrict__ kb, ushort_t* __restrict__ vt)
{
    __shared__ ushort_t Vs[64][72];
    const int blk   = blockIdx.x;
    const int ttile = blk & 15;
    const int bh    = blk >> 4;
    const int b     = bh / H_;
    const int h     = bh % H_;
    const int tid   = threadIdx.x;
    const int tr    = tid >> 2;
    const int dc    = (tid & 3) * 16;
    const int t0    = ttile * 64;

    const float* src = qkv + (size_t)(b * T_ + t0 + tr) * 2304 + h * 64 + dc;

    // Q
    {
        const float4* p = (const float4*)src;
        float4 f0 = p[0], f1 = p[1], f2 = p[2], f3 = p[3];
        uint4 w0 = make_uint4(f2bf2(f0.x,f0.y), f2bf2(f0.z,f0.w), f2bf2(f1.x,f1.y), f2bf2(f1.z,f1.w));
        uint4 w1 = make_uint4(f2bf2(f2.x,f2.y), f2bf2(f2.z,f2.w), f2bf2(f3.x,f3.y), f2bf2(f3.z,f3.w));
        uint4* dst = (uint4*)(qb + ((size_t)bh * T_ + t0 + tr) * 64 + dc);
        dst[0] = w0; dst[1] = w1;
    }
    // K
    {
        const float4* p = (const float4*)(src + 768);
        float4 f0 = p[0], f1 = p[1], f2 = p[2], f3 = p[3];
        uint4 w0 = make_uint4(f2bf2(f0.x,f0.y), f2bf2(f0.z,f0.w), f2bf2(f1.x,f1.y), f2bf2(f1.z,f1.w));
        uint4 w1 = make_uint4(f2bf2(f2.x,f2.y), f2bf2(f2.z,f2.w), f2bf2(f3.x,f3.y), f2bf2(f3.z,f3.w));
        uint4* dst = (uint4*)(kb + ((size_t)bh * T_ + t0 + tr) * 64 + dc);
        dst[0] = w0; dst[1] = w1;
    }
    // V -> LDS (bf16), then transposed out
    {
        const float4* p = (const float4*)(src + 1536);
        float4 f0 = p[0], f1 = p[1], f2 = p[2], f3 = p[3];
        uint_t* dst = (uint_t*)&Vs[tr][dc];
        dst[0] = f2bf2(f0.x,f0.y); dst[1] = f2bf2(f0.z,f0.w);
        dst[2] = f2bf2(f1.x,f1.y); dst[3] = f2bf2(f1.z,f1.w);
        dst[4] = f2bf2(f2.x,f2.y); dst[5] = f2bf2(f2.z,f2.w);
        dst[6] = f2bf2(f3.x,f3.y); dst[7] = f2bf2(f3.z,f3.w);
    }
    __syncthreads();
    {
        const int d  = tid >> 2;
        const int jc = (tid & 3) * 16;
        uint_t w[8];
        #pragma unroll
        for (int i = 0; i < 8; ++i)
            w[i] = (uint_t)Vs[jc + 2*i][d] | ((uint_t)Vs[jc + 2*i + 1][d] << 16);
        uint4* dst = (uint4*)(vt + ((size_t)bh * 64 + d) * T_ + t0 + jc);
        dst[0] = make_uint4(w[0], w[1], w[2], w[3]);
        dst[1] = make_uint4(w[4], w[5], w[6], w[7]);
    }
}

// ---------------- MFMA flash attention ----------------
// qb,kb: [bh][t][64] bf16 ; vt: [bh][64][t] bf16 ; o: [B,T,768] fp32 (slice h*64)
__global__ __launch_bounds__(256) void attn_mfma(const ushort_t* __restrict__ qb,
    const ushort_t* __restrict__ kb, const ushort_t* __restrict__ vt,
    float* __restrict__ o)
{
    __shared__ ushort_t Ks[64 * 72];
    __shared__ ushort_t Vts[64 * 72];
    __shared__ ushort_t Ps[4][16 * 72];

    const int bid = blockIdx.x;
    const int qt  = 15 - (bid & 15);     // heavy blocks first
    const int bh  = bid >> 4;
    const int b   = bh / H_;
    const int h   = bh % H_;
    const int tid  = threadIdx.x;
    const int wq   = tid >> 6;           // wave id -> q sub-tile
    const int lane = tid & 63;
    const int l15  = lane & 15;
    const int lg   = lane >> 4;
    const int qbase = qt * 64;

    // Q fragments (A-operand): row=l15, k=(lg)*8, kc in {0,1} for d=0..63
    bf16x8 qf0, qf1;
    {
        const ushort_t* qp = qb + ((size_t)bh * T_ + qbase + wq * 16 + l15) * 64 + lg * 8;
        qf0 = *(const bf16x8*)qp;
        qf1 = *(const bf16x8*)(qp + 32);
    }

    f32x4 od[4] = {};
    float mr[4] = {-INFINITY, -INFINITY, -INFINITY, -INFINITY};
    float lr[4] = {0.f, 0.f, 0.f, 0.f};

    const int tr = tid >> 2;
    const int cb = (tid & 3) * 16;
    const ushort_t* kgp = kb + ((size_t)bh * T_ + tr) * 64 + cb;
    const ushort_t* vgp = vt + ((size_t)bh * 64 + tr) * T_ + cb;

    for (int jt = 0; jt <= qt; ++jt) {
        // stage K tile [64 rows j][64 cols d] and Vt tile [64 rows d][64 cols j]
        {
            const uint4* ks = (const uint4*)(kgp + (size_t)jt * 64 * 64);
            uint4 k0 = ks[0], k1 = ks[1];
            const uint4* vs = (const uint4*)(vgp + jt * 64);
            uint4 v0 = vs[0], v1 = vs[1];
            *(uint4*)&Ks[tr * 72 + cb]      = k0;
            *(uint4*)&Ks[tr * 72 + cb + 8]  = k1;
            *(uint4*)&Vts[tr * 72 + cb]     = v0;
            *(uint4*)&Vts[tr * 72 + cb + 8] = v1;
        }
        __syncthreads();

        // S = Q @ K^T : 4 n-tiles (j), 2 k-chunks (d)
        f32x4 s[4];
        #pragma unroll
        for (int n = 0; n < 4; ++n) {
            const ushort_t* kr = &Ks[(16 * n + l15) * 72 + lg * 8];
            bf16x8 kf0 = *(const bf16x8*)kr;
            bf16x8 kf1 = *(const bf16x8*)(kr + 32);
            f32x4 acc = {};
            acc = __builtin_amdgcn_mfma_f32_16x16x32_bf16(qf0, kf0, acc, 0, 0, 0);
            acc = __builtin_amdgcn_mfma_f32_16x16x32_bf16(qf1, kf1, acc, 0, 0, 0);
            s[n] = acc;
        }

        // scale + causal mask (diagonal tile only)
        const bool diag = (jt == qt);
        #pragma unroll
        for (int n = 0; n < 4; ++n) {
            #pragma unroll
            for (int r = 0; r < 4; ++r) {
                float v = s[n][r] * 0.125f;
                if (diag) {
                    int jg = 16 * n + l15;
                    int qg = wq * 16 + lg * 4 + r;
                    if (jg > qg) v = -INFINITY;
                }
                s[n][r] = v;
            }
        }

        // online softmax: row = (lg)*4 + r, spread over 16 lanes (l15)
        float al[4];
        #pragma unroll
        for (int r = 0; r < 4; ++r) {
            float tm = fmaxf(fmaxf(s[0][r], s[1][r]), fmaxf(s[2][r], s[3][r]));
            tm = fmaxf(tm, __shfl_xor(tm, 1, 64));
            tm = fmaxf(tm, __shfl_xor(tm, 2, 64));
            tm = fmaxf(tm, __shfl_xor(tm, 4, 64));
            tm = fmaxf(tm, __shfl_xor(tm, 8, 64));
            float mn = fmaxf(mr[r], tm);
            al[r] = __expf(mr[r] - mn);
            mr[r] = mn;
        }
        #pragma unroll
        for (int n = 0; n < 4; ++n)
            #pragma unroll
            for (int r = 0; r < 4; ++r)
                s[n][r] = __expf(s[n][r] - mr[r]);
        #pragma unroll
        for (int r = 0; r < 4; ++r) {
            float ps = s[0][r] + s[1][r] + s[2][r] + s[3][r];
            ps += __shfl_xor(ps, 1, 64);
            ps += __shfl_xor(ps, 2, 64);
            ps += __shfl_xor(ps, 4, 64);
            ps += __shfl_xor(ps, 8, 64);
            lr[r] = lr[r] * al[r] + ps;
        }
        #pragma unroll
        for (int n = 0; n < 4; ++n)
            #pragma unroll
            for (int r = 0; r < 4; ++r)
                od[n][r] *= al[r];

        // P -> LDS (bf16), re-layout S-frag (q=lg*4+r, j=16n+l15) to rows
        #pragma unroll
        for (int n = 0; n < 4; ++n)
            #pragma unroll
            for (int r = 0; r < 4; ++r)
                Ps[wq][(lg * 4 + r) * 72 + 16 * n + l15] = (ushort_t)f2bf1(s[n][r]);

        // O += P @ V : A-frag from Ps (row=q=l15, k=j), B-frag from Vts (row=d, contiguous j)
        #pragma unroll
        for (int kc = 0; kc < 2; ++kc) {
            bf16x8 pa = *(const bf16x8*)&Ps[wq][l15 * 72 + kc * 32 + lg * 8];
            #pragma unroll
            for (int n = 0; n < 4; ++n) {
                bf16x8 vf = *(const bf16x8*)&Vts[(16 * n + l15) * 72 + kc * 32 + lg * 8];
                od[n] = __builtin_amdgcn_mfma_f32_16x16x32_bf16(pa, vf, od[n], 0, 0, 0);
            }
        }
        __syncthreads();
    }

    // write O / l
    #pragma unroll
    for (int r = 0; r < 4; ++r) {
        float inv = 1.0f / lr[r];
        int row = qbase + wq * 16 + lg * 4 + r;
        float* op = o + ((size_t)(b * T_ + row)) * 768 + h * 64 + l15;
        #pragma unroll
        for (int n = 0; n < 4; ++n)
            op[16 * n] = od[n][r] * inv;
    }
}

// ---------------- layernorm over D=768, one block per row ----------------
__global__ __launch_bounds__(256) void ln_kernel(const float* __restrict__ x,
    const float* __restrict__ w, const float* __restrict__ bia, float* __restrict__ out)
{
    const int row = blockIdx.x;
    const int tid = threadIdx.x;
    const float* xr = x + (size_t)row * 768;
    float v0 = xr[tid], v1 = xr[tid + 256], v2 = xr[tid + 512];
    float s  = v0 + v1 + v2;
    float s2 = v0 * v0 + v1 * v1 + v2 * v2;
    #pragma unroll
    for (int off = 32; off > 0; off >>= 1) {
        s  += __shfl_down(s,  off, 64);
        s2 += __shfl_down(s2, off, 64);
    }
    __shared__ float sh[8];
    const int wave = tid >> 6;
    if ((tid & 63) == 0) { sh[wave] = s; sh[4 + wave] = s2; }
    __syncthreads();
    float S  = sh[0] + sh[1] + sh[2] + sh[3];
    float S2 = sh[4] + sh[5] + sh[6] + sh[7];
    float mean = S * (1.f / 768.f);
    float var  = S2 * (1.f / 768.f) - mean * mean;
    float inv  = rsqrtf(var + 1e-5f);
    float* orow = out + (size_t)row * 768;
    orow[tid]       = (v0 - mean) * inv * w[tid]       + bia[tid];
    orow[tid + 256] = (v1 - mean) * inv * w[tid + 256] + bia[tid + 256];
    orow[tid + 512] = (v2 - mean) * inv * w[tid + 512] + bia[tid + 512];
}

// ---------------- embedding ----------------
__global__ __launch_bounds__(256) void embed_kernel(const int* __restrict__ ids,
    const float* __restrict__ tok, const float* __restrict__ pos, float* __restrict__ x)
{
    const int bt = blockIdx.x;
    const int t  = bt % T_;
    const int id = ids[bt];
    const int tid = threadIdx.x;
    const float* tr = tok + (size_t)id * 768;
    const float* pr = pos + (size_t)t * 768;
    float* xr = x + (size_t)bt * 768;
    xr[tid]       = tr[tid]       + pr[tid];
    xr[tid + 256] = tr[tid + 256] + pr[tid + 256];
    xr[tid + 512] = tr[tid + 512] + pr[tid + 512];
}

// ---------------- launcher ----------------
extern "C" void kernel_launch(void* const* d_in, const int* in_sizes, int n_in,
                              void* d_out, int out_size, void* d_ws, size_t ws_size,
                              hipStream_t stream)
{
    const int*   ids   = (const int*)  d_in[0];
    const float* tok   = (const float*)d_in[1];
    const float* pos   = (const float*)d_in[2];
    const float* ln1w  = (const float*)d_in[3];
    const float* ln1b  = (const float*)d_in[4];
    const float* qkvw  = (const float*)d_in[5];
    const float* outw  = (const float*)d_in[6];
    const float* ln2w  = (const float*)d_in[7];
    const float* ln2b  = (const float*)d_in[8];
    const float* upw   = (const float*)d_in[9];
    const float* downw = (const float*)d_in[10];
    const float* lnfw  = (const float*)d_in[11];
    const float* lnfb  = (const float*)d_in[12];
    float* out = (float*)d_out;

    // workspace layout (fp32): x, h, qkv, o, ffh  = 63 MB total
    float* x   = (float*)d_ws;
    float* h   = x   + (size_t)BT_ * D_;
    float* qkv = h   + (size_t)BT_ * D_;
    float* o   = qkv + (size_t)BT_ * 3 * D_;
    float* ffh = o   + (size_t)BT_ * D_;

    // attn prep buffers alias ffh (disjoint lifetimes within a layer):
    // qb/kb: [24][1024][64] bf16 ; vt: [24][64][1024] bf16  (9.4 MB < 25 MB)
    ushort_t* qb = (ushort_t*)ffh;
    ushort_t* kb = qb + (size_t)B_ * H_ * T_ * 64;
    ushort_t* vt = kb + (size_t)B_ * H_ * T_ * 64;

    embed_kernel<<<BT_, 256, 0, stream>>>(ids, tok, pos, x);

    for (int l = 0; l < L_; ++l) {
        ln_kernel<<<BT_, 256, 0, stream>>>(x, ln1w + l * D_, ln1b + l * D_, h);
        gemm_nt<EPI_NONE><<<dim3(3 * D_ / 128, BT_ / 128), 256, 0, stream>>>(
            h, qkvw + (size_t)l * 3 * D_ * D_, nullptr, qkv, BT_, 3 * D_, D_);
        qkv_prep<<<B_ * H_ * (T_ / 64), 256, 0, stream>>>(qkv, qb, kb, vt);
        attn_mfma<<<B_ * H_ * (T_ / 64), 256, 0, stream>>>(qb, kb, vt, o);
        gemm_nt<EPI_RESID><<<dim3(D_ / 128, BT_ / 128), 256, 0, stream>>>(
            o, outw + (size_t)l * D_ * D_, x, x, BT_, D_, D_);
        ln_kernel<<<BT_, 256, 0, stream>>>(x, ln2w + l * D_, ln2b + l * D_, h);
        gemm_nt<EPI_GELU><<<dim3(FF_ / 128, BT_ / 128), 256, 0, stream>>>(
            h, upw + (size_t)l * FF_ * D_, nullptr, ffh, BT_, FF_, D_);
        gemm_nt<EPI_RESID><<<dim3(D_ / 128, BT_ / 128), 256, 0, stream>>>(
            ffh, downw + (size_t)l * D_ * FF_, x, x, BT_, D_, FF_);
    }

    ln_kernel<<<BT_, 256, 0, stream>>>(x, lnfw, lnfb, h);
    gemm_nt<EPI_NONE><<<dim3(V_ / 128, BT_ / 128), 256, 0, stream>>>(
        h, tok, nullptr, out, BT_, V_, D_);
}

// Round 3
// 2211.144 us; speedup vs baseline: 5.9991x; 1.8979x over previous
//
#include <hip/hip_runtime.h>
#include <hip/hip_bf16.h>
#include <math.h>

#define L_  12
#define H_  12
#define D_  768
#define FF_ 3072
#define V_  32000
#define T_  1024
#define B_  2
#define BT_ (B_*T_)

typedef unsigned short ushort_t;
typedef unsigned int   uint_t;
typedef __bf16 bf16x8 __attribute__((ext_vector_type(8)));
typedef float  f32x4  __attribute__((ext_vector_type(4)));

__device__ __forceinline__ uint_t f2bf1(float f) {
    uint_t u = __builtin_bit_cast(uint_t, f);
    return (u + 0x7FFFu + ((u >> 16) & 1u)) >> 16;   // RNE truncate to bf16
}
__device__ __forceinline__ uint_t f2bf2(float lo, float hi) {
    return f2bf1(lo) | (f2bf1(hi) << 16);
}

__device__ __forceinline__ void gl_lds16(const ushort_t* g, ushort_t* l) {
    __builtin_amdgcn_global_load_lds(
        (const __attribute__((address_space(1))) uint_t*)g,
        (__attribute__((address_space(3))) uint_t*)l, 16, 0, 0);
}

// ---------------- weight cast kernels ----------------
__global__ __launch_bounds__(256) void cast_bf16(const float* __restrict__ in,
                                                 ushort_t* __restrict__ out, int n8)
{
    for (int i = blockIdx.x * 256 + threadIdx.x; i < n8; i += gridDim.x * 256) {
        const float4* p = (const float4*)(in + (size_t)i * 8);
        float4 a = p[0], b = p[1];
        *(uint4*)(out + (size_t)i * 8) =
            make_uint4(f2bf2(a.x,a.y), f2bf2(a.z,a.w), f2bf2(b.x,b.y), f2bf2(b.z,b.w));
    }
}

// one layer's {qkv_w, out_w, up_w, down_w} -> contiguous bf16 buffer
__global__ __launch_bounds__(256) void cast_layer(const float* __restrict__ q,
    const float* __restrict__ o, const float* __restrict__ u, const float* __restrict__ d,
    ushort_t* __restrict__ out)
{
    const int N0 = 3*D_*D_/8, N1 = N0 + D_*D_/8, N2 = N1 + FF_*D_/8, N3 = N2 + D_*FF_/8;
    for (int i = blockIdx.x * 256 + threadIdx.x; i < N3; i += gridDim.x * 256) {
        const float* src;
        if      (i < N0) src = q + (size_t)i * 8;
        else if (i < N1) src = o + (size_t)(i - N0) * 8;
        else if (i < N2) src = u + (size_t)(i - N1) * 8;
        else             src = d + (size_t)(i - N2) * 8;
        const float4* p = (const float4*)src;
        float4 a = p[0], b = p[1];
        *(uint4*)(out + (size_t)i * 8) =
            make_uint4(f2bf2(a.x,a.y), f2bf2(a.z,a.w), f2bf2(b.x,b.y), f2bf2(b.z,b.w));
    }
}

// ---------------- GEMM: C[M,N] (+)= A[M,K] @ W[N,K]^T, bf16 in, m97 structure ----------------
#define EPI_F32   0
#define EPI_BF16  1
#define EPI_GELU  2
#define EPI_ATOM  3

template <int EPI>
__global__ __launch_bounds__(256) void gemm_bt(
    const ushort_t* __restrict__ A, const ushort_t* __restrict__ W,
    void* __restrict__ Cv, int N, int K, int MT, int KS, int Kc)
{
    __shared__ ushort_t As[128 * 32];   // linear: global_load_lds forbids padding
    __shared__ ushort_t Bs[128 * 32];

    const int tid  = threadIdx.x;
    const int w    = tid >> 6;
    const int lane = tid & 63;

    // XCD-aware swizzle (nwg % 8 == 0 for all our shapes), then M-fastest decode
    const int nwg = gridDim.x;
    int swz = (blockIdx.x & 7) * (nwg >> 3) + (blockIdx.x >> 3);
    const int mt   = swz % MT;
    int rest       = swz / MT;
    const int ks   = rest % KS;
    const int nt   = rest / KS;
    const int m0 = mt * 128, n0 = nt * 128;
    const int kb = ks * Kc,  ke = kb + Kc;

    // staging: wave w, issue i covers rows w*32+i*16 + lane/4, cols (lane&3)*8..+8
    const int srow = lane >> 2;
    const int scol = (lane & 3) * 8;
    const ushort_t* gA = A + (size_t)(m0 + w * 32 + srow) * K + scol;
    const ushort_t* gW = W + (size_t)(n0 + w * 32 + srow) * K + scol;
    ushort_t* lA = As + w * 1024;
    ushort_t* lB = Bs + w * 1024;
    const size_t row16 = (size_t)16 * K;

    const int lr = lane & 15;
    const int lk = (lane >> 4) * 8;
    const int wm = (w >> 1) * 64;
    const int wn = (w & 1) * 64;

    f32x4 acc[4][4] = {};

    for (int k0 = kb; k0 < ke; k0 += 32) {
        gl_lds16(gA + k0,         lA);
        gl_lds16(gA + k0 + row16, lA + 512);
        gl_lds16(gW + k0,         lB);
        gl_lds16(gW + k0 + row16, lB + 512);
        __syncthreads();   // compiler drains vmcnt before barrier

        bf16x8 av[4], bv[4];
        #pragma unroll
        for (int i = 0; i < 4; ++i)
            av[i] = *(const bf16x8*)&As[(wm + i * 16 + lr) * 32 + lk];
        #pragma unroll
        for (int j = 0; j < 4; ++j)
            bv[j] = *(const bf16x8*)&Bs[(wn + j * 16 + lr) * 32 + lk];
        #pragma unroll
        for (int i = 0; i < 4; ++i)
            #pragma unroll
            for (int j = 0; j < 4; ++j)
                acc[i][j] = __builtin_amdgcn_mfma_f32_16x16x32_bf16(av[i], bv[j], acc[i][j], 0, 0, 0);
        __syncthreads();
    }

    float*    Cf = (float*)Cv;
    ushort_t* Cb = (ushort_t*)Cv;
    const int rbase = (lane >> 4) * 4;
    #pragma unroll
    for (int i = 0; i < 4; ++i) {
        #pragma unroll
        for (int j = 0; j < 4; ++j) {
            #pragma unroll
            for (int r = 0; r < 4; ++r) {
                int row = m0 + wm + i * 16 + rbase + r;
                int col = n0 + wn + j * 16 + lr;
                size_t idx = (size_t)row * N + col;
                float v = acc[i][j][r];
                if (EPI == EPI_F32)  Cf[idx] = v;
                if (EPI == EPI_BF16) Cb[idx] = (ushort_t)f2bf1(v);
                if (EPI == EPI_GELU) Cb[idx] = (ushort_t)f2bf1(0.5f * v * (1.0f + erff(v * 0.70710678118654752f)));
                if (EPI == EPI_ATOM) atomicAdd(&Cf[idx], v);
            }
        }
    }
}

// ---------------- V transpose: qkv bf16 V-slice -> vt[bh][64][T] ----------------
__global__ __launch_bounds__(256) void vprep(const ushort_t* __restrict__ qkv,
                                             ushort_t* __restrict__ vt)
{
    __shared__ ushort_t Vs[64][72];
    const int blk   = blockIdx.x;
    const int ttile = blk & 15;
    const int bh    = blk >> 4;
    const int b     = bh / H_;
    const int h     = bh % H_;
    const int tid   = threadIdx.x;
    const int t0    = ttile * 64;
    {
        const int tr = tid >> 2;
        const int dc = (tid & 3) * 16;
        const uint4* src = (const uint4*)(qkv + (size_t)(b * T_ + t0 + tr) * 2304 + 1536 + h * 64 + dc);
        uint4 v0 = src[0], v1 = src[1];
        *(uint4*)&Vs[tr][dc]     = v0;
        *(uint4*)&Vs[tr][dc + 8] = v1;
    }
    __syncthreads();
    {
        const int d  = tid >> 2;
        const int jc = (tid & 3) * 16;
        uint_t w[8];
        #pragma unroll
        for (int i = 0; i < 8; ++i)
            w[i] = (uint_t)Vs[jc + 2*i][d] | ((uint_t)Vs[jc + 2*i + 1][d] << 16);
        uint4* dst = (uint4*)(vt + ((size_t)bh * 64 + d) * T_ + t0 + jc);
        dst[0] = make_uint4(w[0], w[1], w[2], w[3]);
        dst[1] = make_uint4(w[4], w[5], w[6], w[7]);
    }
}

// ---------------- MFMA flash attention (Q,K direct from qkv bf16; V from vt) ----------------
__global__ __launch_bounds__(256) void attn_mfma(const ushort_t* __restrict__ qkv,
    const ushort_t* __restrict__ vt, ushort_t* __restrict__ o)
{
    __shared__ ushort_t Ks[64 * 72];
    __shared__ ushort_t Vts[64 * 72];
    __shared__ ushort_t Ps[4][16 * 72];

    const int bid = blockIdx.x;
    const int qt  = 15 - (bid & 15);     // heavy blocks first
    const int bh  = bid >> 4;
    const int b   = bh / H_;
    const int h   = bh % H_;
    const int tid  = threadIdx.x;
    const int wq   = tid >> 6;
    const int lane = tid & 63;
    const int l15  = lane & 15;
    const int lg   = lane >> 4;
    const int qbase = qt * 64;

    // Q fragments straight from qkv
    bf16x8 qf0, qf1;
    {
        const ushort_t* qp = qkv + (size_t)(b * T_ + qbase + wq * 16 + l15) * 2304 + h * 64 + lg * 8;
        qf0 = *(const bf16x8*)qp;
        qf1 = *(const bf16x8*)(qp + 32);
    }

    f32x4 od[4] = {};
    float mr[4] = {-INFINITY, -INFINITY, -INFINITY, -INFINITY};
    float lr[4] = {0.f, 0.f, 0.f, 0.f};

    const int tr = tid >> 2;
    const int cb = (tid & 3) * 16;
    const ushort_t* kgp = qkv + (size_t)(b * T_ + tr) * 2304 + 768 + h * 64 + cb;
    const ushort_t* vgp = vt + ((size_t)bh * 64 + tr) * T_ + cb;

    for (int jt = 0; jt <= qt; ++jt) {
        {
            const uint4* ks = (const uint4*)(kgp + (size_t)jt * 64 * 2304);
            uint4 k0 = ks[0], k1 = ks[1];
            const uint4* vs = (const uint4*)(vgp + jt * 64);
            uint4 v0 = vs[0], v1 = vs[1];
            *(uint4*)&Ks[tr * 72 + cb]      = k0;
            *(uint4*)&Ks[tr * 72 + cb + 8]  = k1;
            *(uint4*)&Vts[tr * 72 + cb]     = v0;
            *(uint4*)&Vts[tr * 72 + cb + 8] = v1;
        }
        __syncthreads();

        f32x4 s[4];
        #pragma unroll
        for (int n = 0; n < 4; ++n) {
            const ushort_t* kr = &Ks[(16 * n + l15) * 72 + lg * 8];
            bf16x8 kf0 = *(const bf16x8*)kr;
            bf16x8 kf1 = *(const bf16x8*)(kr + 32);
            f32x4 a = {};
            a = __builtin_amdgcn_mfma_f32_16x16x32_bf16(qf0, kf0, a, 0, 0, 0);
            a = __builtin_amdgcn_mfma_f32_16x16x32_bf16(qf1, kf1, a, 0, 0, 0);
            s[n] = a;
        }

        const bool diag = (jt == qt);
        #pragma unroll
        for (int n = 0; n < 4; ++n) {
            #pragma unroll
            for (int r = 0; r < 4; ++r) {
                float v = s[n][r] * 0.125f;
                if (diag) {
                    int jg = 16 * n + l15;
                    int qg = wq * 16 + lg * 4 + r;
                    if (jg > qg) v = -INFINITY;
                }
                s[n][r] = v;
            }
        }

        float al[4];
        #pragma unroll
        for (int r = 0; r < 4; ++r) {
            float tm = fmaxf(fmaxf(s[0][r], s[1][r]), fmaxf(s[2][r], s[3][r]));
            tm = fmaxf(tm, __shfl_xor(tm, 1, 64));
            tm = fmaxf(tm, __shfl_xor(tm, 2, 64));
            tm = fmaxf(tm, __shfl_xor(tm, 4, 64));
            tm = fmaxf(tm, __shfl_xor(tm, 8, 64));
            float mn = fmaxf(mr[r], tm);
            al[r] = __expf(mr[r] - mn);
            mr[r] = mn;
        }
        #pragma unroll
        for (int n = 0; n < 4; ++n)
            #pragma unroll
            for (int r = 0; r < 4; ++r)
                s[n][r] = __expf(s[n][r] - mr[r]);
        #pragma unroll
        for (int r = 0; r < 4; ++r) {
            float ps = s[0][r] + s[1][r] + s[2][r] + s[3][r];
            ps += __shfl_xor(ps, 1, 64);
            ps += __shfl_xor(ps, 2, 64);
            ps += __shfl_xor(ps, 4, 64);
            ps += __shfl_xor(ps, 8, 64);
            lr[r] = lr[r] * al[r] + ps;
        }
        #pragma unroll
        for (int n = 0; n < 4; ++n)
            #pragma unroll
            for (int r = 0; r < 4; ++r)
                od[n][r] *= al[r];

        #pragma unroll
        for (int n = 0; n < 4; ++n)
            #pragma unroll
            for (int r = 0; r < 4; ++r)
                Ps[wq][(lg * 4 + r) * 72 + 16 * n + l15] = (ushort_t)f2bf1(s[n][r]);

        #pragma unroll
        for (int kc = 0; kc < 2; ++kc) {
            bf16x8 pa = *(const bf16x8*)&Ps[wq][l15 * 72 + kc * 32 + lg * 8];
            #pragma unroll
            for (int n = 0; n < 4; ++n) {
                bf16x8 vf = *(const bf16x8*)&Vts[(16 * n + l15) * 72 + kc * 32 + lg * 8];
                od[n] = __builtin_amdgcn_mfma_f32_16x16x32_bf16(pa, vf, od[n], 0, 0, 0);
            }
        }
        __syncthreads();
    }

    #pragma unroll
    for (int r = 0; r < 4; ++r) {
        float inv = 1.0f / lr[r];
        int row = qbase + wq * 16 + lg * 4 + r;
        ushort_t* op = o + ((size_t)(b * T_ + row)) * 768 + h * 64 + l15;
        #pragma unroll
        for (int n = 0; n < 4; ++n)
            op[16 * n] = (ushort_t)f2bf1(od[n][r] * inv);
    }
}

// ---------------- layernorm: fp32 in, bf16 out ----------------
__global__ __launch_bounds__(256) void ln_kernel(const float* __restrict__ x,
    const float* __restrict__ w, const float* __restrict__ bia, ushort_t* __restrict__ out)
{
    const int row = blockIdx.x;
    const int tid = threadIdx.x;
    const float* xr = x + (size_t)row * 768;
    float v0 = xr[tid], v1 = xr[tid + 256], v2 = xr[tid + 512];
    float s  = v0 + v1 + v2;
    float s2 = v0 * v0 + v1 * v1 + v2 * v2;
    #pragma unroll
    for (int off = 32; off > 0; off >>= 1) {
        s  += __shfl_down(s,  off, 64);
        s2 += __shfl_down(s2, off, 64);
    }
    __shared__ float sh[8];
    const int wave = tid >> 6;
    if ((tid & 63) == 0) { sh[wave] = s; sh[4 + wave] = s2; }
    __syncthreads();
    float S  = sh[0] + sh[1] + sh[2] + sh[3];
    float S2 = sh[4] + sh[5] + sh[6] + sh[7];
    float mean = S * (1.f / 768.f);
    float var  = S2 * (1.f / 768.f) - mean * mean;
    float inv  = rsqrtf(var + 1e-5f);
    ushort_t* orow = out + (size_t)row * 768;
    orow[tid]       = (ushort_t)f2bf1((v0 - mean) * inv * w[tid]       + bia[tid]);
    orow[tid + 256] = (ushort_t)f2bf1((v1 - mean) * inv * w[tid + 256] + bia[tid + 256]);
    orow[tid + 512] = (ushort_t)f2bf1((v2 - mean) * inv * w[tid + 512] + bia[tid + 512]);
}

// ---------------- embedding ----------------
__global__ __launch_bounds__(256) void embed_kernel(const int* __restrict__ ids,
    const float* __restrict__ tok, const float* __restrict__ pos, float* __restrict__ x)
{
    const int bt = blockIdx.x;
    const int t  = bt % T_;
    const int id = ids[bt];
    const int tid = threadIdx.x;
    const float* tr = tok + (size_t)id * 768;
    const float* pr = pos + (size_t)t * 768;
    float* xr = x + (size_t)bt * 768;
    xr[tid]       = tr[tid]       + pr[tid];
    xr[tid + 256] = tr[tid + 256] + pr[tid + 256];
    xr[tid + 512] = tr[tid + 512] + pr[tid + 512];
}

// ---------------- launcher ----------------
extern "C" void kernel_launch(void* const* d_in, const int* in_sizes, int n_in,
                              void* d_out, int out_size, void* d_ws, size_t ws_size,
                              hipStream_t stream)
{
    const int*   ids   = (const int*)  d_in[0];
    const float* tok   = (const float*)d_in[1];
    const float* pos   = (const float*)d_in[2];
    const float* ln1w  = (const float*)d_in[3];
    const float* ln1b  = (const float*)d_in[4];
    const float* qkvw  = (const float*)d_in[5];
    const float* outw  = (const float*)d_in[6];
    const float* ln2w  = (const float*)d_in[7];
    const float* ln2b  = (const float*)d_in[8];
    const float* upw   = (const float*)d_in[9];
    const float* downw = (const float*)d_in[10];
    const float* lnfw  = (const float*)d_in[11];
    const float* lnfb  = (const float*)d_in[12];
    float* out = (float*)d_out;

    // workspace (52.3 MB): h | x | qkv | o | vt | ffh | layerW ; tokW aliases x..end
    char* ws = (char*)d_ws;
    ushort_t* h    = (ushort_t*)ws;                               // 3,145,728 B
    float*    x    = (float*)   (ws + 3145728);                   // 6,291,456 B
    ushort_t* qkv  = (ushort_t*)(ws + 9437184);                   // 9,437,184 B
    ushort_t* o    = qkv  + (size_t)BT_ * 3 * D_;                 // 3,145,728 B
    ushort_t* vt   = o    + (size_t)BT_ * D_;                     // 3,145,728 B
    ushort_t* ffh  = vt   + (size_t)B_ * H_ * 64 * T_;            // 12,582,912 B
    ushort_t* layerW = ffh + (size_t)BT_ * FF_;                   // 14,155,776 B
    ushort_t* tokW = (ushort_t*)(ws + 3145728);                   // aliases x.. (49.15 MB)

    ushort_t* qkvwB  = layerW;
    ushort_t* outwB  = qkvwB + (size_t)3 * D_ * D_;
    ushort_t* upwB   = outwB + (size_t)D_ * D_;
    ushort_t* downwB = upwB  + (size_t)FF_ * D_;

    embed_kernel<<<BT_, 256, 0, stream>>>(ids, tok, pos, x);

    for (int l = 0; l < L_; ++l) {
        cast_layer<<<1024, 256, 0, stream>>>(
            qkvw  + (size_t)l * 3 * D_ * D_,
            outw  + (size_t)l * D_ * D_,
            upw   + (size_t)l * FF_ * D_,
            downw + (size_t)l * D_ * FF_, layerW);

        ln_kernel<<<BT_, 256, 0, stream>>>(x, ln1w + l * D_, ln1b + l * D_, h);

        gemm_bt<EPI_BF16><<<16 * (3 * D_ / 128), 256, 0, stream>>>(
            h, qkvwB, qkv, 3 * D_, D_, 16, 1, D_);

        vprep<<<B_ * H_ * (T_ / 64), 256, 0, stream>>>(qkv, vt);
        attn_mfma<<<B_ * H_ * (T_ / 64), 256, 0, stream>>>(qkv, vt, o);

        gemm_bt<EPI_ATOM><<<16 * (D_ / 128) * 2, 256, 0, stream>>>(
            o, outwB, x, D_, D_, 16, 2, D_ / 2);

        ln_kernel<<<BT_, 256, 0, stream>>>(x, ln2w + l * D_, ln2b + l * D_, h);

        gemm_bt<EPI_GELU><<<16 * (FF_ / 128), 256, 0, stream>>>(
            h, upwB, ffh, FF_, D_, 16, 1, D_);

        gemm_bt<EPI_ATOM><<<16 * (D_ / 128) * 4, 256, 0, stream>>>(
            ffh, downwB, x, D_, FF_, 16, 4, FF_ / 4);
    }

    ln_kernel<<<BT_, 256, 0, stream>>>(x, lnfw, lnfb, h);
    cast_bf16<<<2048, 256, 0, stream>>>(tok, tokW, V_ * D_ / 8);
    gemm_bt<EPI_F32><<<16 * (V_ / 128), 256, 0, stream>>>(
        h, tokW, out, V_, D_, 16, 1, D_);
}

// Round 4
// 2194.679 us; speedup vs baseline: 6.0441x; 1.0075x over previous
//
#include <hip/hip_runtime.h>
#include <hip/hip_bf16.h>
#include <math.h>

#define L_  12
#define H_  12
#define D_  768
#define FF_ 3072
#define V_  32000
#define T_  1024
#define B_  2
#define BT_ (B_*T_)

typedef unsigned short ushort_t;
typedef unsigned int   uint_t;
typedef __bf16 bf16x8 __attribute__((ext_vector_type(8)));
typedef float  f32x4  __attribute__((ext_vector_type(4)));

__device__ __forceinline__ uint_t f2bf1(float f) {
    uint_t u = __builtin_bit_cast(uint_t, f);
    return (u + 0x7FFFu + ((u >> 16) & 1u)) >> 16;   // RNE truncate to bf16
}
__device__ __forceinline__ uint_t f2bf2(float lo, float hi) {
    return f2bf1(lo) | (f2bf1(hi) << 16);
}

__device__ __forceinline__ void gl_lds16(const ushort_t* g, ushort_t* l) {
    __builtin_amdgcn_global_load_lds(
        (const __attribute__((address_space(1))) uint_t*)g,
        (__attribute__((address_space(3))) uint_t*)l, 16, 0, 0);
}

// ---------------- weight cast kernels ----------------
__global__ __launch_bounds__(256) void cast_bf16(const float* __restrict__ in,
                                                 ushort_t* __restrict__ out, int n8)
{
    for (int i = blockIdx.x * 256 + threadIdx.x; i < n8; i += gridDim.x * 256) {
        const float4* p = (const float4*)(in + (size_t)i * 8);
        float4 a = p[0], b = p[1];
        *(uint4*)(out + (size_t)i * 8) =
            make_uint4(f2bf2(a.x,a.y), f2bf2(a.z,a.w), f2bf2(b.x,b.y), f2bf2(b.z,b.w));
    }
}

// one layer's {qkv_w, out_w, up_w, down_w} -> contiguous bf16 buffer
__global__ __launch_bounds__(256) void cast_layer(const float* __restrict__ q,
    const float* __restrict__ o, const float* __restrict__ u, const float* __restrict__ d,
    ushort_t* __restrict__ out)
{
    const int N0 = 3*D_*D_/8, N1 = N0 + D_*D_/8, N2 = N1 + FF_*D_/8, N3 = N2 + D_*FF_/8;
    for (int i = blockIdx.x * 256 + threadIdx.x; i < N3; i += gridDim.x * 256) {
        const float* src;
        if      (i < N0) src = q + (size_t)i * 8;
        else if (i < N1) src = o + (size_t)(i - N0) * 8;
        else if (i < N2) src = u + (size_t)(i - N1) * 8;
        else             src = d + (size_t)(i - N2) * 8;
        const float4* p = (const float4*)src;
        float4 a = p[0], b = p[1];
        *(uint4*)(out + (size_t)i * 8) =
            make_uint4(f2bf2(a.x,a.y), f2bf2(a.z,a.w), f2bf2(b.x,b.y), f2bf2(b.z,b.w));
    }
}

// ---------------- GEMM: C[M,N] (+)= A[M,K] @ W[N,K]^T, bf16, BK=64, XOR-swizzled LDS ----------------
#define EPI_F32   0
#define EPI_BF16  1
#define EPI_GELU  2
#define EPI_ATOM  3

template <int EPI, int KS>
__global__ __launch_bounds__(256) void gemm_bt(
    const ushort_t* __restrict__ A, const ushort_t* __restrict__ W,
    void* __restrict__ Cv, int N, int K, int Kc)
{
    __shared__ ushort_t As[128 * 64];   // linear dest (global_load_lds); content chunk-swizzled
    __shared__ ushort_t Bs[128 * 64];

    const int tid  = threadIdx.x;
    const int w    = tid >> 6;
    const int lane = tid & 63;

    // XCD-aware swizzle (nwg % 8 == 0 for all our shapes), then M-fastest decode (MT=16)
    const int nwg = gridDim.x;
    int swz = (blockIdx.x & 7) * (nwg >> 3) + (blockIdx.x >> 3);
    const int mt   = swz & 15;
    int rest       = swz >> 4;
    const int ks   = rest & (KS - 1);
    const int nt   = rest / KS;
    const int m0 = mt * 128, n0 = nt * 128;
    const int kb = ks * Kc,  ke = kb + Kc;

    // staging: wave w stages rows w*32..w*32+31 per operand, 4 issues of 8 rows.
    // source col chunk is XOR'd with (ldsrow & 7) so the LINEAR lds write lands swizzled.
    const int srow = lane >> 3;                       // 0..7
    const int scol = ((lane & 7) ^ srow) * 8;         // inverse-swizzled global chunk
    const ushort_t* gA = A + (size_t)(m0 + w * 32 + srow) * K + scol;
    const ushort_t* gW = W + (size_t)(n0 + w * 32 + srow) * K + scol;
    ushort_t* lA = As + w * 2048;
    ushort_t* lB = Bs + w * 2048;
    const size_t row8 = (size_t)8 * K;

    const int lr = lane & 15;
    const int lg = lane >> 4;
    const int wm = (w >> 1) * 64;
    const int wn = (w & 1) * 64;

    f32x4 acc[4][4] = {};

    for (int k0 = kb; k0 < ke; k0 += 64) {
        #pragma unroll
        for (int i = 0; i < 4; ++i) {
            gl_lds16(gA + k0 + i * row8, lA + i * 512);
            gl_lds16(gW + k0 + i * row8, lB + i * 512);
        }
        __syncthreads();   // compiler drains vmcnt before barrier

        #pragma unroll
        for (int kk = 0; kk < 2; ++kk) {
            bf16x8 av[4], bv[4];
            #pragma unroll
            for (int i = 0; i < 4; ++i) {
                int rr = wm + i * 16 + lr;
                int ch = (lg + 4 * kk) ^ (rr & 7);
                av[i] = *(const bf16x8*)&As[rr * 64 + ch * 8];
            }
            #pragma unroll
            for (int j = 0; j < 4; ++j) {
                int rr = wn + j * 16 + lr;
                int ch = (lg + 4 * kk) ^ (rr & 7);
                bv[j] = *(const bf16x8*)&Bs[rr * 64 + ch * 8];
            }
            #pragma unroll
            for (int i = 0; i < 4; ++i)
                #pragma unroll
                for (int j = 0; j < 4; ++j)
                    acc[i][j] = __builtin_amdgcn_mfma_f32_16x16x32_bf16(av[i], bv[j], acc[i][j], 0, 0, 0);
        }
        __syncthreads();
    }

    float*    Cf = (float*)Cv;
    ushort_t* Cb = (ushort_t*)Cv;
    const int rbase = (lane >> 4) * 4;
    #pragma unroll
    for (int i = 0; i < 4; ++i) {
        #pragma unroll
        for (int j = 0; j < 4; ++j) {
            #pragma unroll
            for (int r = 0; r < 4; ++r) {
                int row = m0 + wm + i * 16 + rbase + r;
                int col = n0 + wn + j * 16 + lr;
                size_t idx = (size_t)row * N + col;
                float v = acc[i][j][r];
                if (EPI == EPI_F32)  Cf[idx] = v;
                if (EPI == EPI_BF16) Cb[idx] = (ushort_t)f2bf1(v);
                if (EPI == EPI_GELU) Cb[idx] = (ushort_t)f2bf1(0.5f * v * (1.0f + erff(v * 0.70710678118654752f)));
                if (EPI == EPI_ATOM) atomicAdd(&Cf[idx], v);
            }
        }
    }
}

// ---------------- V transpose: qkv bf16 V-slice -> vt[bh][64][T] ----------------
__global__ __launch_bounds__(256) void vprep(const ushort_t* __restrict__ qkv,
                                             ushort_t* __restrict__ vt)
{
    __shared__ ushort_t Vs[64][72];
    const int blk   = blockIdx.x;
    const int ttile = blk & 15;
    const int bh    = blk >> 4;
    const int b     = bh / H_;
    const int h     = bh % H_;
    const int tid   = threadIdx.x;
    const int t0    = ttile * 64;
    {
        const int tr = tid >> 2;
        const int dc = (tid & 3) * 16;
        const uint4* src = (const uint4*)(qkv + (size_t)(b * T_ + t0 + tr) * 2304 + 1536 + h * 64 + dc);
        uint4 v0 = src[0], v1 = src[1];
        *(uint4*)&Vs[tr][dc]     = v0;
        *(uint4*)&Vs[tr][dc + 8] = v1;
    }
    __syncthreads();
    {
        const int d  = tid >> 2;
        const int jc = (tid & 3) * 16;
        uint_t w[8];
        #pragma unroll
        for (int i = 0; i < 8; ++i)
            w[i] = (uint_t)Vs[jc + 2*i][d] | ((uint_t)Vs[jc + 2*i + 1][d] << 16);
        uint4* dst = (uint4*)(vt + ((size_t)bh * 64 + d) * T_ + t0 + jc);
        dst[0] = make_uint4(w[0], w[1], w[2], w[3]);
        dst[1] = make_uint4(w[4], w[5], w[6], w[7]);
    }
}

// ---------------- MFMA flash attention, no-LDS K/V (L2-resident), 1 wave / 16 q-rows ----------------
__global__ __launch_bounds__(64) void attn_mfma(const ushort_t* __restrict__ qkv,
    const ushort_t* __restrict__ vt, ushort_t* __restrict__ o)
{
    __shared__ ushort_t Ps[16 * 136];

    // bh-clustered XCD swizzle: 1536 blocks -> 8 chunks of 192 (3 bh each)
    int swz = (blockIdx.x & 7) * 192 + (blockIdx.x >> 3);
    const int bh  = swz >> 6;
    const int qtl = 63 - (swz & 63);     // heavy q-tiles first within chunk
    const int b   = bh / H_;
    const int h   = bh % H_;
    const int lane = threadIdx.x;
    const int l15  = lane & 15;
    const int lg   = lane >> 4;
    const int qbase = qtl * 16;
    const int qlast = qbase + 15;

    const ushort_t* qp = qkv + ((size_t)(b * T_) + qbase + l15) * 2304 + h * 64 + lg * 8;
    bf16x8 qf0 = *(const bf16x8*)qp;
    bf16x8 qf1 = *(const bf16x8*)(qp + 32);

    f32x4 od[4] = {};
    float mr[4] = {-INFINITY, -INFINITY, -INFINITY, -INFINITY};
    float lr[4] = {0.f, 0.f, 0.f, 0.f};

    const ushort_t* kbase = qkv + (size_t)(b * T_) * 2304 + 768 + h * 64;
    const ushort_t* vbase = vt + (size_t)bh * 64 * T_;
    const float SC = 0.18033688011112042f;   // 0.125 * log2(e): softmax in exp2 domain

    for (int j0 = 0; j0 <= qlast; j0 += 128) {
        f32x4 s[8];
        __builtin_amdgcn_s_setprio(1);
        #pragma unroll
        for (int n = 0; n < 8; ++n) {
            if (j0 + 16 * n <= qlast) {
                const ushort_t* kr = kbase + (size_t)(j0 + 16 * n + l15) * 2304 + lg * 8;
                bf16x8 kf0 = *(const bf16x8*)kr;
                bf16x8 kf1 = *(const bf16x8*)(kr + 32);
                f32x4 a = {};
                a = __builtin_amdgcn_mfma_f32_16x16x32_bf16(qf0, kf0, a, 0, 0, 0);
                a = __builtin_amdgcn_mfma_f32_16x16x32_bf16(qf1, kf1, a, 0, 0, 0);
                s[n] = a;
            } else {
                s[n] = f32x4{-INFINITY, -INFINITY, -INFINITY, -INFINITY};
            }
        }
        __builtin_amdgcn_s_setprio(0);

        #pragma unroll
        for (int n = 0; n < 8; ++n) {
            #pragma unroll
            for (int r = 0; r < 4; ++r) {
                float v = s[n][r] * SC;
                int jg = j0 + 16 * n + l15;
                int qg = qbase + lg * 4 + r;
                if (jg > qg) v = -INFINITY;
                s[n][r] = v;
            }
        }

        float al[4];
        #pragma unroll
        for (int r = 0; r < 4; ++r) {
            float tm = fmaxf(fmaxf(fmaxf(s[0][r], s[1][r]), fmaxf(s[2][r], s[3][r])),
                             fmaxf(fmaxf(s[4][r], s[5][r]), fmaxf(s[6][r], s[7][r])));
            tm = fmaxf(tm, __shfl_xor(tm, 1, 64));
            tm = fmaxf(tm, __shfl_xor(tm, 2, 64));
            tm = fmaxf(tm, __shfl_xor(tm, 4, 64));
            tm = fmaxf(tm, __shfl_xor(tm, 8, 64));
            float mn = fmaxf(mr[r], tm);
            al[r] = exp2f(mr[r] - mn);
            mr[r] = mn;
        }
        #pragma unroll
        for (int n = 0; n < 8; ++n)
            #pragma unroll
            for (int r = 0; r < 4; ++r)
                s[n][r] = exp2f(s[n][r] - mr[r]);
        #pragma unroll
        for (int r = 0; r < 4; ++r) {
            float ps = (s[0][r] + s[1][r]) + (s[2][r] + s[3][r]);
            ps += (s[4][r] + s[5][r]) + (s[6][r] + s[7][r]);
            ps += __shfl_xor(ps, 1, 64);
            ps += __shfl_xor(ps, 2, 64);
            ps += __shfl_xor(ps, 4, 64);
            ps += __shfl_xor(ps, 8, 64);
            lr[r] = lr[r] * al[r] + ps;
        }
        #pragma unroll
        for (int n = 0; n < 4; ++n)
            #pragma unroll
            for (int r = 0; r < 4; ++r)
                od[n][r] *= al[r];

        // P -> LDS rows (q = lg*4+r, j fast) for the PV A-fragment
        #pragma unroll
        for (int n = 0; n < 8; ++n)
            #pragma unroll
            for (int r = 0; r < 4; ++r)
                Ps[(lg * 4 + r) * 136 + 16 * n + l15] = (ushort_t)f2bf1(s[n][r]);

        __builtin_amdgcn_s_setprio(1);
        #pragma unroll
        for (int kc = 0; kc < 4; ++kc) {
            if (j0 + kc * 32 <= qlast) {
                bf16x8 pa = *(const bf16x8*)&Ps[l15 * 136 + kc * 32 + lg * 8];
                #pragma unroll
                for (int nn = 0; nn < 4; ++nn) {
                    bf16x8 vf = *(const bf16x8*)&vbase[(size_t)(16 * nn + l15) * T_ + j0 + kc * 32 + lg * 8];
                    od[nn] = __builtin_amdgcn_mfma_f32_16x16x32_bf16(pa, vf, od[nn], 0, 0, 0);
                }
            }
        }
        __builtin_amdgcn_s_setprio(0);
    }

    #pragma unroll
    for (int r = 0; r < 4; ++r) {
        float inv = 1.0f / lr[r];
        int row = qbase + lg * 4 + r;
        ushort_t* op = o + ((size_t)(b * T_ + row)) * 768 + h * 64 + l15;
        #pragma unroll
        for (int nn = 0; nn < 4; ++nn)
            op[16 * nn] = (ushort_t)f2bf1(od[nn][r] * inv);
    }
}

// ---------------- layernorm: fp32 in, bf16 out ----------------
__global__ __launch_bounds__(256) void ln_kernel(const float* __restrict__ x,
    const float* __restrict__ w, const float* __restrict__ bia, ushort_t* __restrict__ out)
{
    const int row = blockIdx.x;
    const int tid = threadIdx.x;
    const float* xr = x + (size_t)row * 768;
    float v0 = xr[tid], v1 = xr[tid + 256], v2 = xr[tid + 512];
    float s  = v0 + v1 + v2;
    float s2 = v0 * v0 + v1 * v1 + v2 * v2;
    #pragma unroll
    for (int off = 32; off > 0; off >>= 1) {
        s  += __shfl_down(s,  off, 64);
        s2 += __shfl_down(s2, off, 64);
    }
    __shared__ float sh[8];
    const int wave = tid >> 6;
    if ((tid & 63) == 0) { sh[wave] = s; sh[4 + wave] = s2; }
    __syncthreads();
    float S  = sh[0] + sh[1] + sh[2] + sh[3];
    float S2 = sh[4] + sh[5] + sh[6] + sh[7];
    float mean = S * (1.f / 768.f);
    float var  = S2 * (1.f / 768.f) - mean * mean;
    float inv  = rsqrtf(var + 1e-5f);
    ushort_t* orow = out + (size_t)row * 768;
    orow[tid]       = (ushort_t)f2bf1((v0 - mean) * inv * w[tid]       + bia[tid]);
    orow[tid + 256] = (ushort_t)f2bf1((v1 - mean) * inv * w[tid + 256] + bia[tid + 256]);
    orow[tid + 512] = (ushort_t)f2bf1((v2 - mean) * inv * w[tid + 512] + bia[tid + 512]);
}

// ---------------- embedding ----------------
__global__ __launch_bounds__(256) void embed_kernel(const int* __restrict__ ids,
    const float* __restrict__ tok, const float* __restrict__ pos, float* __restrict__ x)
{
    const int bt = blockIdx.x;
    const int t  = bt % T_;
    const int id = ids[bt];
    const int tid = threadIdx.x;
    const float* tr = tok + (size_t)id * 768;
    const float* pr = pos + (size_t)t * 768;
    float* xr = x + (size_t)bt * 768;
    xr[tid]       = tr[tid]       + pr[tid];
    xr[tid + 256] = tr[tid + 256] + pr[tid + 256];
    xr[tid + 512] = tr[tid + 512] + pr[tid + 512];
}

// ---------------- launcher ----------------
extern "C" void kernel_launch(void* const* d_in, const int* in_sizes, int n_in,
                              void* d_out, int out_size, void* d_ws, size_t ws_size,
                              hipStream_t stream)
{
    const int*   ids   = (const int*)  d_in[0];
    const float* tok   = (const float*)d_in[1];
    const float* pos   = (const float*)d_in[2];
    const float* ln1w  = (const float*)d_in[3];
    const float* ln1b  = (const float*)d_in[4];
    const float* qkvw  = (const float*)d_in[5];
    const float* outw  = (const float*)d_in[6];
    const float* ln2w  = (const float*)d_in[7];
    const float* ln2b  = (const float*)d_in[8];
    const float* upw   = (const float*)d_in[9];
    const float* downw = (const float*)d_in[10];
    const float* lnfw  = (const float*)d_in[11];
    const float* lnfb  = (const float*)d_in[12];
    float* out = (float*)d_out;

    // workspace (52.3 MB): h | x | qkv | o | vt | ffh | layerW ; tokW aliases x..end
    char* ws = (char*)d_ws;
    ushort_t* h    = (ushort_t*)ws;                               // 3,145,728 B
    float*    x    = (float*)   (ws + 3145728);                   // 6,291,456 B
    ushort_t* qkv  = (ushort_t*)(ws + 9437184);                   // 9,437,184 B
    ushort_t* o    = qkv  + (size_t)BT_ * 3 * D_;                 // 3,145,728 B
    ushort_t* vt   = o    + (size_t)BT_ * D_;                     // 3,145,728 B
    ushort_t* ffh  = vt   + (size_t)B_ * H_ * 64 * T_;            // 12,582,912 B
    ushort_t* layerW = ffh + (size_t)BT_ * FF_;                   // 14,155,776 B
    ushort_t* tokW = (ushort_t*)(ws + 3145728);                   // aliases x.. (49.15 MB)

    ushort_t* qkvwB  = layerW;
    ushort_t* outwB  = qkvwB + (size_t)3 * D_ * D_;
    ushort_t* upwB   = outwB + (size_t)D_ * D_;
    ushort_t* downwB = upwB  + (size_t)FF_ * D_;

    embed_kernel<<<BT_, 256, 0, stream>>>(ids, tok, pos, x);

    for (int l = 0; l < L_; ++l) {
        cast_layer<<<1024, 256, 0, stream>>>(
            qkvw  + (size_t)l * 3 * D_ * D_,
            outw  + (size_t)l * D_ * D_,
            upw   + (size_t)l * FF_ * D_,
            downw + (size_t)l * D_ * FF_, layerW);

        ln_kernel<<<BT_, 256, 0, stream>>>(x, ln1w + l * D_, ln1b + l * D_, h);

        gemm_bt<EPI_BF16, 1><<<16 * (3 * D_ / 128), 256, 0, stream>>>(
            h, qkvwB, qkv, 3 * D_, D_, D_);

        vprep<<<B_ * H_ * (T_ / 64), 256, 0, stream>>>(qkv, vt);
        attn_mfma<<<B_ * H_ * (T_ / 16), 64, 0, stream>>>(qkv, vt, o);

        gemm_bt<EPI_ATOM, 2><<<16 * (D_ / 128) * 2, 256, 0, stream>>>(
            o, outwB, x, D_, D_, D_ / 2);

        ln_kernel<<<BT_, 256, 0, stream>>>(x, ln2w + l * D_, ln2b + l * D_, h);

        gemm_bt<EPI_GELU, 1><<<16 * (FF_ / 128), 256, 0, stream>>>(
            h, upwB, ffh, FF_, D_, D_);

        gemm_bt<EPI_ATOM, 4><<<16 * (D_ / 128) * 4, 256, 0, stream>>>(
            ffh, downwB, x, D_, FF_, FF_ / 4);
    }

    ln_kernel<<<BT_, 256, 0, stream>>>(x, lnfw, lnfb, h);
    cast_bf16<<<2048, 256, 0, stream>>>(tok, tokW, V_ * D_ / 8);
    gemm_bt<EPI_F32, 1><<<16 * (V_ / 128), 256, 0, stream>>>(
        h, tokW, out, V_, D_, D_);
}